// Round 19
// baseline (460.825 us; speedup 1.0000x reference)
//
#include <hip/hip_runtime.h>

#define NT 8192
#define DM 1024

typedef unsigned short u16;
typedef __bf16 bf16x8 __attribute__((ext_vector_type(8)));
typedef float f32x4 __attribute__((ext_vector_type(4)));
typedef u16 u16x8 __attribute__((ext_vector_type(8)));

__device__ __forceinline__ u16 f2bf(float f) {
  union { float f; unsigned u; } v; v.f = f;
  unsigned r = v.u + 0x7fffu + ((v.u >> 16) & 1u);
  return (u16)(r >> 16);
}
__device__ __forceinline__ float bf2f(u16 h) {
  union { unsigned u; float f; } v; v.u = ((unsigned)h) << 16;
  return v.f;
}

__device__ __forceinline__ void stage16(const u16* g, u16* lds_wave_uniform) {
  __builtin_amdgcn_global_load_lds(
      (const __attribute__((address_space(1))) unsigned int*)g,
      (__attribute__((address_space(3))) unsigned int*)lds_wave_uniform, 16, 0, 0);
}

// ---------------- f32 -> bf16 convert: X, Wq, Wk, Wv in one launch ----------------
__global__ void cvt_all_kernel(const float* __restrict__ X, const float* __restrict__ Wq,
                               const float* __restrict__ Wk, const float* __restrict__ Wv,
                               u16* __restrict__ Xb, u16* __restrict__ Wqb,
                               u16* __restrict__ Wkb, u16* __restrict__ Wvb) {
  const int NX = NT * DM / 4;
  const int NW = DM * DM / 4;
  const int total = NX + 3 * NW;
  int i = blockIdx.x * blockDim.x + threadIdx.x;
  int stride = gridDim.x * blockDim.x;
  for (; i < total; i += stride) {
    const float* src; u16* dst; int j;
    if (i < NX)               { src = X;  dst = Xb;  j = i; }
    else if (i < NX + NW)     { src = Wq; dst = Wqb; j = i - NX; }
    else if (i < NX + 2 * NW) { src = Wk; dst = Wkb; j = i - NX - NW; }
    else                      { src = Wv; dst = Wvb; j = i - NX - 2 * NW; }
    float4 v = reinterpret_cast<const float4*>(src)[j];
    ushort4 o;
    o.x = f2bf(v.x); o.y = f2bf(v.y); o.z = f2bf(v.z); o.w = f2bf(v.w);
    reinterpret_cast<ushort4*>(dst)[j] = o;
  }
}

// ============ 256x256 8-wave BK=64 QK^T + exp + colsum epilogue ============
// Round-19: r18-proven barrier-top + counted-vmcnt(8) ordering (loads get a
// full K-tile of latency cover; never drain to 0 in the main loop). Staging
// geometry, XOR involution, 4 quadrant-phases, and epilogue unchanged from
// the r8/13/16/18-proven kernel.
__global__ __launch_bounds__(512, 2)
void qkt_exp_256(const u16* __restrict__ Q, const u16* __restrict__ Kmat, int K, int lda,
                 u16* __restrict__ E, float* __restrict__ cs,
                 const int* __restrict__ indp) {
  __shared__ u16 AT[2][256 * 64];
  __shared__ u16 BT[2][256 * 64];
  const int t = threadIdx.x;
  const int l = t & 63;
  const int w = t >> 6;
  const int wm = w >> 2;
  const int wn = w & 3;
  const int r16 = l & 15;
  const int half = l >> 4;

  const int gx = gridDim.x;
  const int nwg = gx * gridDim.y;
  int lin = blockIdx.y * gx + blockIdx.x;
  if ((nwg & 7) == 0) lin = (lin & 7) * (nwg >> 3) + (lin >> 3);
  const int bx = lin % gx;
  const int by = lin / gx;
  const size_t brow = (size_t)by * 256;
  const size_t bcol = (size_t)bx * 256;

  const int srow = w * 8 + (l >> 3);
  const int kel = ((l & 7) ^ (l >> 3)) * 8;
  const int ntiles = K >> 6;

  f32x4 acc[8][4] = {};

#define QSTAGE(tile, buf)                                                             \
  {                                                                                   \
    const int k0_ = (tile) << 6;                                                      \
    _Pragma("unroll")                                                                 \
    for (int q = 0; q < 4; ++q)                                                       \
      stage16(Q + (brow + q * 64 + srow) * (size_t)lda + (k0_ + kel),                 \
              &AT[buf][q * 4096 + w * 512]);                                          \
    _Pragma("unroll")                                                                 \
    for (int q = 0; q < 4; ++q)                                                       \
      stage16(Kmat + (bcol + q * 64 + srow) * (size_t)lda + (k0_ + kel),              \
              &BT[buf][q * 4096 + w * 512]);                                          \
  }

  QSTAGE(0, 0);

  for (int tt = 0; tt < ntiles; ++tt) {
    const int cur = tt & 1;
    __builtin_amdgcn_s_barrier();
    __builtin_amdgcn_sched_barrier(0);   // race safety: nothing hoists above barrier
    if (tt + 1 < ntiles) {
      QSTAGE(tt + 1, cur ^ 1);
      __builtin_amdgcn_sched_barrier(0); // pin staging issue before the wait
      asm volatile("s_waitcnt vmcnt(8)" ::: "memory");  // tile t's 8 done; t+1's in flight
    } else {
      asm volatile("s_waitcnt vmcnt(0)" ::: "memory");
    }

#pragma unroll
    for (int p = 0; p < 4; ++p) {
      bf16x8 af[4][2], bfr[2][2];
#pragma unroll
      for (int m = 0; m < 4; ++m) {
        const int row = wm * 128 + (p >> 1) * 64 + m * 16 + r16;
#pragma unroll
        for (int kk = 0; kk < 2; ++kk) {
          const int slot = (half + 4 * kk) ^ (r16 & 7);
          af[m][kk] = *reinterpret_cast<const bf16x8*>(&AT[cur][row * 64 + slot * 8]);
        }
      }
#pragma unroll
      for (int n = 0; n < 2; ++n) {
        const int row = wn * 64 + (p & 1) * 32 + n * 16 + r16;
#pragma unroll
        for (int kk = 0; kk < 2; ++kk) {
          const int slot = (half + 4 * kk) ^ (r16 & 7);
          bfr[n][kk] = *reinterpret_cast<const bf16x8*>(&BT[cur][row * 64 + slot * 8]);
        }
      }
      __builtin_amdgcn_s_setprio(1);
#pragma unroll
      for (int m = 0; m < 4; ++m)
#pragma unroll
        for (int n = 0; n < 2; ++n)
#pragma unroll
          for (int kk = 0; kk < 2; ++kk)
            acc[(p >> 1) * 4 + m][(p & 1) * 2 + n] = __builtin_amdgcn_mfma_f32_16x16x32_bf16(
                af[m][kk], bfr[n][kk], acc[(p >> 1) * 4 + m][(p & 1) * 2 + n], 0, 0, 0);
      __builtin_amdgcn_s_setprio(0);
      __builtin_amdgcn_sched_barrier(0);
    }
  }
#undef QSTAGE

  const bool flip = (*indp == 0);
  const float cexp = 0.045084220027780106f;  // log2(e)/sqrt(1024)
  float csum[4] = {0.f, 0.f, 0.f, 0.f};
#pragma unroll
  for (int mg = 0; mg < 8; ++mg) {
#pragma unroll
    for (int ng = 0; ng < 4; ++ng) {
#pragma unroll
      for (int q = 0; q < 4; ++q) {
        float s = acc[mg][ng][q];
        float x = flip ? (1.0f - s) : s;
        float e = exp2f(x * cexp);
        size_t row = brow + wm * 128 + mg * 16 + half * 4 + q;
        size_t col = bcol + wn * 64 + ng * 16 + r16;
        E[row * NT + col] = f2bf(e);
        csum[ng] += e;
      }
    }
  }
#pragma unroll
  for (int ng = 0; ng < 4; ++ng) {
    float s = csum[ng];
    s += __shfl_xor(s, 16);
    s += __shfl_xor(s, 32);
    if (l < 16) atomicAdd(&cs[bcol + wn * 64 + ng * 16 + l], s);
  }
}

// ========== Unified C = A @ B^T, 128x128 tile, 8 waves (2M x 4N), BK=64 ==========
// (round-18 proven: double-buffered 64 KB LDS, 2 blocks/CU, counted vmcnt(4).)
// EPI 0: QK-proj: obf = bf16(acc + bias[col]), bias = b0/b1 by col segment
// EPI 2: PV: of32 = acc
// EPI 4: VT: obf = bf16((acc + b0[row]) / csp[col])
template<int EPI>
__global__ __launch_bounds__(512, 4)
void mega_bt(const u16* __restrict__ A, const u16* __restrict__ B, int K,
             int lda, int ldb, int ldo,
             const float* __restrict__ b0, const float* __restrict__ b1,
             const float* __restrict__ csp,
             u16* __restrict__ obf, float* __restrict__ of32) {
  __shared__ u16 AT[2][128 * 64];
  __shared__ u16 BT[2][128 * 64];
  const int t = threadIdx.x;
  const int l = t & 63;
  const int w = t >> 6;
  const int wm = w >> 2;      // 0..1  (row group of 64)
  const int wn = w & 3;       // 0..3  (col group of 32)
  const int r16 = l & 15;
  const int half = l >> 4;

  const int gx = gridDim.x;
  const int nwg = gx * gridDim.y;
  int lin = blockIdx.y * gx + blockIdx.x;
  if ((nwg & 7) == 0) lin = (lin & 7) * (nwg >> 3) + (lin >> 3);
  const int bx = lin % gx;
  const int by = lin / gx;
  const size_t brow = (size_t)by * 128;
  const size_t bcol = (size_t)bx * 128;

  const int srow = w * 8 + (l >> 3);
  const int kel = ((l & 7) ^ (l >> 3)) * 8;
  const int nt = K >> 6;

  f32x4 acc[4][2] = {};

#define STAGE(tile, buf)                                                              \
  {                                                                                   \
    const int k0_ = (tile) << 6;                                                      \
    _Pragma("unroll")                                                                 \
    for (int q = 0; q < 2; ++q)                                                       \
      stage16(A + (brow + q * 64 + srow) * (size_t)lda + (k0_ + kel),                 \
              &AT[buf][q * 4096 + w * 512]);                                          \
    _Pragma("unroll")                                                                 \
    for (int q = 0; q < 2; ++q)                                                       \
      stage16(B + (bcol + q * 64 + srow) * (size_t)ldb + (k0_ + kel),                 \
              &BT[buf][q * 4096 + w * 512]);                                          \
  }

  STAGE(0, 0);

  for (int tt = 0; tt < nt; ++tt) {
    const int cur = tt & 1;
    __builtin_amdgcn_s_barrier();
    __builtin_amdgcn_sched_barrier(0);   // race safety: nothing hoists above barrier
    if (tt + 1 < nt) {
      STAGE(tt + 1, cur ^ 1);
      __builtin_amdgcn_sched_barrier(0); // pin staging issue before the wait
      asm volatile("s_waitcnt vmcnt(4)" ::: "memory");  // t's 4 done; t+1's in flight
    } else {
      asm volatile("s_waitcnt vmcnt(0)" ::: "memory");
    }

    bf16x8 af[4][2], bfr[2][2];
#pragma unroll
    for (int m = 0; m < 4; ++m) {
      const int row = wm * 64 + m * 16 + r16;
#pragma unroll
      for (int kk = 0; kk < 2; ++kk) {
        const int slot = (half + 4 * kk) ^ (r16 & 7);
        af[m][kk] = *reinterpret_cast<const bf16x8*>(&AT[cur][row * 64 + slot * 8]);
      }
    }
#pragma unroll
    for (int n = 0; n < 2; ++n) {
      const int row = wn * 32 + n * 16 + r16;
#pragma unroll
      for (int kk = 0; kk < 2; ++kk) {
        const int slot = (half + 4 * kk) ^ (r16 & 7);
        bfr[n][kk] = *reinterpret_cast<const bf16x8*>(&BT[cur][row * 64 + slot * 8]);
      }
    }
    __builtin_amdgcn_s_setprio(1);
#pragma unroll
    for (int m = 0; m < 4; ++m)
#pragma unroll
      for (int n = 0; n < 2; ++n)
#pragma unroll
        for (int kk = 0; kk < 2; ++kk)
          acc[m][n] = __builtin_amdgcn_mfma_f32_16x16x32_bf16(
              af[m][kk], bfr[n][kk], acc[m][n], 0, 0, 0);
    __builtin_amdgcn_s_setprio(0);
  }
#undef STAGE

  if constexpr (EPI == 0) {
    const float* bp = ((bcol >> 10) == 0) ? b0 : b1;
#pragma unroll
    for (int mg = 0; mg < 4; ++mg) {
#pragma unroll
      for (int n = 0; n < 2; ++n) {
        const int cc = wn * 32 + n * 16 + r16;
        const float bv = bp[((int)bcol & 1023) + cc];
#pragma unroll
        for (int q = 0; q < 4; ++q) {
          size_t row = brow + wm * 64 + mg * 16 + half * 4 + q;
          obf[row * (size_t)ldo + bcol + cc] = f2bf(acc[mg][n][q] + bv);
        }
      }
    }
  } else if constexpr (EPI == 4) {
#pragma unroll
    for (int n = 0; n < 2; ++n) {
      const int cc = wn * 32 + n * 16 + r16;
      const float invc = 1.0f / csp[bcol + cc];
#pragma unroll
      for (int mg = 0; mg < 4; ++mg) {
#pragma unroll
        for (int q = 0; q < 4; ++q) {
          size_t row = brow + wm * 64 + mg * 16 + half * 4 + q;
          obf[row * (size_t)ldo + bcol + cc] = f2bf((acc[mg][n][q] + b0[row]) * invc);
        }
      }
    }
  } else {
#pragma unroll
    for (int mg = 0; mg < 4; ++mg) {
#pragma unroll
      for (int n = 0; n < 2; ++n) {
#pragma unroll
        for (int q = 0; q < 4; ++q) {
          size_t row = brow + wm * 64 + mg * 16 + half * 4 + q;
          size_t col = bcol + wn * 32 + n * 16 + r16;
          of32[row * (size_t)ldo + col] = acc[mg][n][q];
        }
      }
    }
  }
}

// ---------------- GEMM C = A @ B^T  (m97 structure, fallback path) ----------------
template<int EPI, int AF32, int BF32>
__global__ __launch_bounds__(256)
void gemm_bt(const void* __restrict__ Av, const void* __restrict__ Bv, int K, int ldo,
             const float* __restrict__ bias, u16* __restrict__ obf,
             float* __restrict__ of32, const int* __restrict__ indp) {
  __shared__ u16 As[128 * 32];
  __shared__ u16 Bs[128 * 32];
  const int t = threadIdx.x;
  const int l = t & 63;
  const int w = t >> 6;
  const int wr = w >> 1;
  const int wc = w & 1;
  const int r16 = l & 15;
  const int half = l >> 4;

  const int gx = gridDim.x;
  const int nwg = gx * gridDim.y;
  int lin = blockIdx.y * gx + blockIdx.x;
  if ((nwg & 7) == 0) lin = (lin & 7) * (nwg >> 3) + (lin >> 3);
  const int bx = lin % gx;
  const int by = lin / gx;

  const size_t brow = (size_t)by * 128;
  const size_t bcol = (size_t)bx * 128;
  const int kel = (l & 3) * 8;
  const int lrow = l >> 2;

  f32x4 acc[4][4] = {};

  for (int k0 = 0; k0 < K; k0 += 32) {
#pragma unroll
    for (int c = 0; c < 2; ++c) {
      const int seg = c * 4 + w;
      const int r = seg * 16 + lrow;
      if constexpr (AF32) {
        const float* ga = (const float*)Av + (brow + r) * (size_t)K + (k0 + kel);
        float4 u0 = *reinterpret_cast<const float4*>(ga);
        float4 u1 = *reinterpret_cast<const float4*>(ga + 4);
        u16x8 o;
        o[0] = f2bf(u0.x); o[1] = f2bf(u0.y); o[2] = f2bf(u0.z); o[3] = f2bf(u0.w);
        o[4] = f2bf(u1.x); o[5] = f2bf(u1.y); o[6] = f2bf(u1.z); o[7] = f2bf(u1.w);
        *reinterpret_cast<u16x8*>(&As[seg * 512 + l * 8]) = o;
      } else {
        const u16* ga = (const u16*)Av + (brow + r) * (size_t)K + (k0 + kel);
        stage16(ga, &As[seg * 512]);
      }
      if constexpr (BF32) {
        const float* gb = (const float*)Bv + (bcol + r) * (size_t)K + (k0 + kel);
        float4 u0 = *reinterpret_cast<const float4*>(gb);
        float4 u1 = *reinterpret_cast<const float4*>(gb + 4);
        u16x8 o;
        o[0] = f2bf(u0.x); o[1] = f2bf(u0.y); o[2] = f2bf(u0.z); o[3] = f2bf(u0.w);
        o[4] = f2bf(u1.x); o[5] = f2bf(u1.y); o[6] = f2bf(u1.z); o[7] = f2bf(u1.w);
        *reinterpret_cast<u16x8*>(&Bs[seg * 512 + l * 8]) = o;
      } else {
        const u16* gb = (const u16*)Bv + (bcol + r) * (size_t)K + (k0 + kel);
        stage16(gb, &Bs[seg * 512]);
      }
    }
    __syncthreads();
    bf16x8 af[4], bfv[4];
#pragma unroll
    for (int m = 0; m < 4; ++m)
      af[m] = *reinterpret_cast<const bf16x8*>(&As[(wr * 64 + m * 16 + r16) * 32 + half * 8]);
#pragma unroll
    for (int n = 0; n < 4; ++n)
      bfv[n] = *reinterpret_cast<const bf16x8*>(&Bs[(wc * 64 + n * 16 + r16) * 32 + half * 8]);
#pragma unroll
    for (int m = 0; m < 4; ++m)
#pragma unroll
      for (int n = 0; n < 4; ++n)
        acc[m][n] = __builtin_amdgcn_mfma_f32_16x16x32_bf16(af[m], bfv[n], acc[m][n], 0, 0, 0);
    __syncthreads();
  }

  const int crow0 = wr * 64 + half * 4;
  const int ccol0 = wc * 64 + r16;

  if constexpr (EPI == 0) {
#pragma unroll
    for (int m = 0; m < 4; ++m) {
#pragma unroll
      for (int n = 0; n < 4; ++n) {
        const int cc = ccol0 + n * 16;
        const float bv = bias[bcol + cc];
#pragma unroll
        for (int q = 0; q < 4; ++q) {
          size_t idx = (brow + crow0 + m * 16 + q) * (size_t)ldo + (bcol + cc);
          obf[idx] = f2bf(acc[m][n][q] + bv);
        }
      }
    }
  } else if constexpr (EPI == 1) {
    const bool flip = (*indp == 0);
    const float cexp = 0.045084220027780106f;
#pragma unroll
    for (int m = 0; m < 4; ++m) {
#pragma unroll
      for (int n = 0; n < 4; ++n) {
        const int cc = ccol0 + n * 16;
#pragma unroll
        for (int q = 0; q < 4; ++q) {
          float s = acc[m][n][q];
          float x = flip ? (1.0f - s) : s;
          size_t idx = (brow + crow0 + m * 16 + q) * (size_t)ldo + (bcol + cc);
          of32[idx] = exp2f(x * cexp);
        }
      }
    }
  } else {
#pragma unroll
    for (int m = 0; m < 4; ++m) {
#pragma unroll
      for (int n = 0; n < 4; ++n) {
        const int cc = ccol0 + n * 16;
#pragma unroll
        for (int q = 0; q < 4; ++q) {
          size_t idx = (brow + crow0 + m * 16 + q) * (size_t)ldo + (bcol + cc);
          of32[idx] = acc[m][n][q];
        }
      }
    }
  }
}

// ---------------- column sums (f32 source, fallback) ----------------
__global__ void colsum_kernel(const float* __restrict__ E, float* __restrict__ cs) {
  const int col = blockIdx.x * 256 + threadIdx.x;
  const int r0 = blockIdx.y * 256;
  float s = 0.f;
  for (int r = r0; r < r0 + 256; ++r)
    s += E[(size_t)r * NT + col];
  atomicAdd(&cs[col], s);
}

// ---------------- normalize ----------------
__global__ void norm_kernel(float* __restrict__ w, const float* __restrict__ cs, int n4) {
  int i = blockIdx.x * blockDim.x + threadIdx.x;
  int stride = gridDim.x * blockDim.x;
  for (; i < n4; i += stride) {
    float4 v = reinterpret_cast<float4*>(w)[i];
    int j4 = i & (NT / 4 - 1);
    float4 c = reinterpret_cast<const float4*>(cs)[j4];
    v.x /= c.x; v.y /= c.y; v.z /= c.z; v.w /= c.w;
    reinterpret_cast<float4*>(w)[i] = v;
  }
}

__global__ void norm_bf16_kernel(const u16* __restrict__ e, float* __restrict__ w,
                                 const float* __restrict__ cs, int n4) {
  int i = blockIdx.x * blockDim.x + threadIdx.x;
  int stride = gridDim.x * blockDim.x;
  for (; i < n4; i += stride) {
    ushort4 ev = reinterpret_cast<const ushort4*>(e)[i];
    int j4 = i & (NT / 4 - 1);
    float4 c = reinterpret_cast<const float4*>(cs)[j4];
    float4 v;
    v.x = bf2f(ev.x) / c.x;
    v.y = bf2f(ev.y) / c.y;
    v.z = bf2f(ev.z) / c.z;
    v.w = bf2f(ev.w) / c.w;
    reinterpret_cast<float4*>(w)[i] = v;
  }
}

// ---- Vt[d][j] = Vb[j][d] (fallback transpose) ----
__global__ void vt_kernel(const u16* __restrict__ Vb, const float* __restrict__ cs,
                          u16* __restrict__ Vt) {
  __shared__ u16 tile[64][65];
  const int jb = blockIdx.x * 64;
  const int db = blockIdx.y * 64;
  const int t = threadIdx.x;
  {
    const int d = t & 63;
    const int j0 = t >> 6;
    for (int jj = j0; jj < 64; jj += 4)
      tile[jj][d] = Vb[(size_t)(jb + jj) * DM + db + d];
  }
  __syncthreads();
  {
    const int j = t & 63;
    const int d0 = t >> 6;
    const float inv = cs ? (1.0f / cs[jb + j]) : 1.0f;
    for (int dd = d0; dd < 64; dd += 4) {
      u16 raw = tile[j][dd];
      Vt[(size_t)(db + dd) * NT + jb + j] = cs ? f2bf(bf2f(raw) * inv) : raw;
    }
  }
}

extern "C" void kernel_launch(void* const* d_in, const int* in_sizes, int n_in,
                              void* d_out, int out_size, void* d_ws, size_t ws_size,
                              hipStream_t stream) {
  const float* X  = (const float*)d_in[0];
  const int* indp = (const int*)d_in[1];
  const float* Wq = (const float*)d_in[2];
  const float* bq = (const float*)d_in[3];
  const float* Wk = (const float*)d_in[4];
  const float* bk = (const float*)d_in[5];
  const float* Wv = (const float*)d_in[6];
  const float* bv = (const float*)d_in[7];

  float* attn_out = (float*)d_out;                       // [NT, DM]
  float* attn_w   = (float*)d_out + (size_t)NT * DM;     // [NT, NT]

  const size_t EB_BYTES = (size_t)NT * NT * 2;           // 128 MB
  const size_t QKV_BYTES = (size_t)NT * DM * 2;          // 16.8 MB
  const size_t need_fast = EB_BYTES + 4 * QKV_BYTES + NT * 4;

  if (ws_size >= need_fast) {
    // ---------------- FAST PATH ----------------
    // Layout: Eb | QKb (NT x 2048) | Vt (DM x NT) | Xb | Wvb | cs
    char* ws = (char*)d_ws;
    u16* Eb  = (u16*)ws;
    u16* QKb = (u16*)(ws + EB_BYTES);                    // [NT][2048]
    u16* Vt  = QKb + (size_t)NT * 2048;                  // [DM][NT]
    u16* Xb  = Vt + (size_t)DM * NT;                     // [NT][DM]
    u16* Wvb = Xb + (size_t)NT * DM;                     // [DM][DM]
    float* cs = (float*)(Wvb + (size_t)DM * DM);
    // Wq/Wk packed bf16 live in the dead Eb region: [2048][1024]
    u16* Wqkb = Eb;
    u16* Wqb = Wqkb;
    u16* Wkb = Wqkb + (size_t)DM * DM;

    cvt_all_kernel<<<2048, 256, 0, stream>>>(X, Wq, Wk, Wv, Xb, Wqb, Wkb, Wvb);

    // QK projection (fused): QKb = X @ [Wq;Wk]^T + [bq;bk]  (ldo = 2048)
    mega_bt<0><<<dim3(2048 / 128, NT / 128), 512, 0, stream>>>(
        Xb, Wqkb, DM, DM, DM, 2048, bq, bk, nullptr, QKb, nullptr);

    // QK^T + exp -> bf16 E, fused column sums (Q = QKb cols 0..1023, K = cols 1024..2047)
    hipMemsetAsync(cs, 0, NT * sizeof(float), stream);
    qkt_exp_256<<<dim3(NT / 256, NT / 256), 512, 0, stream>>>(
        QKb, QKb + 1024, DM, 2048, Eb, cs, indp);

    // Vt = (Wv @ X^T + bv[row]) / cs[col]  -> bf16 [DM][NT]
    mega_bt<4><<<dim3(NT / 128, DM / 128), 512, 0, stream>>>(
        Wvb, Xb, DM, DM, DM, NT, bv, nullptr, cs, Vt, nullptr);

    // attn_out = Eb @ Vt^T (EPI2)
    mega_bt<2><<<dim3(DM / 128, NT / 128), 512, 0, stream>>>(
        Eb, Vt, NT, NT, NT, DM, nullptr, nullptr, nullptr, nullptr, attn_out);

    // attn_w = Eb / cs
    norm_bf16_kernel<<<4096, 256, 0, stream>>>(Eb, attn_w, cs, NT * NT / 4);
  } else {
    // ---------------- FALLBACK (round-3 proven path) ----------------
    char* ws = (char*)d_ws;
    u16* Qb = (u16*)ws;  ws += QKV_BYTES;
    u16* Kb = (u16*)ws;  ws += QKV_BYTES;
    u16* Vb = (u16*)ws;  ws += QKV_BYTES;
    u16* Vt = (u16*)ws;  ws += QKV_BYTES;
    float* cs = (float*)ws;

    dim3 gqkv(DM / 128, NT / 128);
    gemm_bt<0, 1, 1><<<gqkv, 256, 0, stream>>>(X, Wq, DM, DM, bq, Qb, nullptr, nullptr);
    gemm_bt<0, 1, 1><<<gqkv, 256, 0, stream>>>(X, Wk, DM, DM, bk, Kb, nullptr, nullptr);
    gemm_bt<0, 1, 1><<<gqkv, 256, 0, stream>>>(X, Wv, DM, DM, bv, Vb, nullptr, nullptr);

    gemm_bt<1, 0, 0><<<dim3(NT / 128, NT / 128), 256, 0, stream>>>(
        Qb, Kb, DM, NT, nullptr, nullptr, attn_w, indp);

    hipMemsetAsync(cs, 0, NT * sizeof(float), stream);
    colsum_kernel<<<dim3(32, 32), 256, 0, stream>>>(attn_w, cs);
    norm_kernel<<<4096, 256, 0, stream>>>(attn_w, cs, NT * NT / 4);
    vt_kernel<<<dim3(NT / 64, DM / 64), 256, 0, stream>>>(Vb, nullptr, Vt);

    gemm_bt<2, 1, 0><<<dim3(DM / 128, NT / 128), 256, 0, stream>>>(
        attn_w, Vt, NT, DM, nullptr, nullptr, attn_out, nullptr);
  }
}

// Round 20
// 440.770 us; speedup vs baseline: 1.0455x; 1.0455x over previous
//
#include <hip/hip_runtime.h>

#define NT 8192
#define DM 1024

typedef unsigned short u16;
typedef __bf16 bf16x8 __attribute__((ext_vector_type(8)));
typedef float f32x4 __attribute__((ext_vector_type(4)));
typedef u16 u16x8 __attribute__((ext_vector_type(8)));

__device__ __forceinline__ u16 f2bf(float f) {
  union { float f; unsigned u; } v; v.f = f;
  unsigned r = v.u + 0x7fffu + ((v.u >> 16) & 1u);
  return (u16)(r >> 16);
}
__device__ __forceinline__ float bf2f(u16 h) {
  union { unsigned u; float f; } v; v.u = ((unsigned)h) << 16;
  return v.f;
}

__device__ __forceinline__ void stage16(const u16* g, u16* lds_wave_uniform) {
  __builtin_amdgcn_global_load_lds(
      (const __attribute__((address_space(1))) unsigned int*)g,
      (__attribute__((address_space(3))) unsigned int*)lds_wave_uniform, 16, 0, 0);
}

// ---------------- f32 -> bf16 convert: X, Wq, Wk, Wv in one launch ----------------
__global__ void cvt_all_kernel(const float* __restrict__ X, const float* __restrict__ Wq,
                               const float* __restrict__ Wk, const float* __restrict__ Wv,
                               u16* __restrict__ Xb, u16* __restrict__ Wqb,
                               u16* __restrict__ Wkb, u16* __restrict__ Wvb) {
  const int NX = NT * DM / 4;
  const int NW = DM * DM / 4;
  const int total = NX + 3 * NW;
  int i = blockIdx.x * blockDim.x + threadIdx.x;
  int stride = gridDim.x * blockDim.x;
  for (; i < total; i += stride) {
    const float* src; u16* dst; int j;
    if (i < NX)               { src = X;  dst = Xb;  j = i; }
    else if (i < NX + NW)     { src = Wq; dst = Wqb; j = i - NX; }
    else if (i < NX + 2 * NW) { src = Wk; dst = Wkb; j = i - NX - NW; }
    else                      { src = Wv; dst = Wvb; j = i - NX - 2 * NW; }
    float4 v = reinterpret_cast<const float4*>(src)[j];
    ushort4 o;
    o.x = f2bf(v.x); o.y = f2bf(v.y); o.z = f2bf(v.z); o.w = f2bf(v.w);
    reinterpret_cast<ushort4*>(dst)[j] = o;
  }
}

// ============ 256x256 8-wave BK=64 QK^T + exp + colsum epilogue ============
// Round-8/13/16/18 proven schedule (185 us, 5 consistent measurements):
// staging split across phases 0/1, per-phase sched_barrier, setprio,
// bank-conflict 0. Schedule-variant probes {r14 hoist: 196, r17 BK32: 231,
// r19 counted-vmcnt: 215} all regressed -> this is the local optimum at
// 1 block/CU.
__global__ __launch_bounds__(512, 2)
void qkt_exp_256(const u16* __restrict__ Q, const u16* __restrict__ Kmat, int K, int lda,
                 u16* __restrict__ E, float* __restrict__ cs,
                 const int* __restrict__ indp) {
  __shared__ u16 AT[2][256 * 64];
  __shared__ u16 BT[2][256 * 64];
  const int t = threadIdx.x;
  const int l = t & 63;
  const int w = t >> 6;
  const int wm = w >> 2;
  const int wn = w & 3;
  const int r16 = l & 15;
  const int half = l >> 4;

  const int gx = gridDim.x;
  const int nwg = gx * gridDim.y;
  int lin = blockIdx.y * gx + blockIdx.x;
  if ((nwg & 7) == 0) lin = (lin & 7) * (nwg >> 3) + (lin >> 3);
  const int bx = lin % gx;
  const int by = lin / gx;
  const size_t brow = (size_t)by * 256;
  const size_t bcol = (size_t)bx * 256;

  const int srow = w * 8 + (l >> 3);
  const int kel = ((l & 7) ^ (l >> 3)) * 8;
  const int ntiles = K >> 6;

  f32x4 acc[8][4] = {};

#pragma unroll
  for (int q = 0; q < 4; ++q) {
    stage16(Q    + (brow + q * 64 + srow) * (size_t)lda + kel, &AT[0][q * 4096 + w * 512]);
    stage16(Kmat + (bcol + q * 64 + srow) * (size_t)lda + kel, &BT[0][q * 4096 + w * 512]);
  }
  __syncthreads();

  for (int tt = 0; tt < ntiles; ++tt) {
    const int cur = tt & 1;
    const int nxt = cur ^ 1;
    const int k1 = (tt + 1) << 6;
    const bool more = (tt + 1 < ntiles);
#pragma unroll
    for (int p = 0; p < 4; ++p) {
      if (p == 0 && more) {
#pragma unroll
        for (int q = 0; q < 4; ++q)
          stage16(Q + (brow + q * 64 + srow) * (size_t)lda + (k1 + kel),
                  &AT[nxt][q * 4096 + w * 512]);
      }
      if (p == 1 && more) {
#pragma unroll
        for (int q = 0; q < 4; ++q)
          stage16(Kmat + (bcol + q * 64 + srow) * (size_t)lda + (k1 + kel),
                  &BT[nxt][q * 4096 + w * 512]);
      }
      bf16x8 af[4][2], bfr[2][2];
#pragma unroll
      for (int m = 0; m < 4; ++m) {
        const int row = wm * 128 + (p >> 1) * 64 + m * 16 + r16;
#pragma unroll
        for (int kk = 0; kk < 2; ++kk) {
          const int slot = (half + 4 * kk) ^ (r16 & 7);
          af[m][kk] = *reinterpret_cast<const bf16x8*>(&AT[cur][row * 64 + slot * 8]);
        }
      }
#pragma unroll
      for (int n = 0; n < 2; ++n) {
        const int row = wn * 64 + (p & 1) * 32 + n * 16 + r16;
#pragma unroll
        for (int kk = 0; kk < 2; ++kk) {
          const int slot = (half + 4 * kk) ^ (r16 & 7);
          bfr[n][kk] = *reinterpret_cast<const bf16x8*>(&BT[cur][row * 64 + slot * 8]);
        }
      }
      __builtin_amdgcn_s_setprio(1);
#pragma unroll
      for (int m = 0; m < 4; ++m)
#pragma unroll
        for (int n = 0; n < 2; ++n)
#pragma unroll
          for (int kk = 0; kk < 2; ++kk)
            acc[(p >> 1) * 4 + m][(p & 1) * 2 + n] = __builtin_amdgcn_mfma_f32_16x16x32_bf16(
                af[m][kk], bfr[n][kk], acc[(p >> 1) * 4 + m][(p & 1) * 2 + n], 0, 0, 0);
      __builtin_amdgcn_s_setprio(0);
      __builtin_amdgcn_sched_barrier(0);
    }
    __syncthreads();
  }

  const bool flip = (*indp == 0);
  const float cexp = 0.045084220027780106f;  // log2(e)/sqrt(1024)
  float csum[4] = {0.f, 0.f, 0.f, 0.f};
#pragma unroll
  for (int mg = 0; mg < 8; ++mg) {
#pragma unroll
    for (int ng = 0; ng < 4; ++ng) {
#pragma unroll
      for (int q = 0; q < 4; ++q) {
        float s = acc[mg][ng][q];
        float x = flip ? (1.0f - s) : s;
        float e = exp2f(x * cexp);
        size_t row = brow + wm * 128 + mg * 16 + half * 4 + q;
        size_t col = bcol + wn * 64 + ng * 16 + r16;
        E[row * NT + col] = f2bf(e);
        csum[ng] += e;
      }
    }
  }
#pragma unroll
  for (int ng = 0; ng < 4; ++ng) {
    float s = csum[ng];
    s += __shfl_xor(s, 16);
    s += __shfl_xor(s, 32);
    if (l < 16) atomicAdd(&cs[bcol + wn * 64 + ng * 16 + l], s);
  }
}

// ========== Unified C = A @ B^T, 128x128 tile, 8 waves (2M x 4N), BK=64 ==========
// Round-18 proven (-43 us): double-buffered 64 KB LDS (2 blocks/CU), barrier-
// top ordering with counted vmcnt(4) — t's loads issued one full K-tile ago.
// EPI 0: QK-proj: obf = bf16(acc + bias[col]), bias = b0/b1 by col segment
// EPI 2: PV: of32 = acc
// EPI 4: VT: obf = bf16((acc + b0[row]) / csp[col])
template<int EPI>
__global__ __launch_bounds__(512, 4)
void mega_bt(const u16* __restrict__ A, const u16* __restrict__ B, int K,
             int lda, int ldb, int ldo,
             const float* __restrict__ b0, const float* __restrict__ b1,
             const float* __restrict__ csp,
             u16* __restrict__ obf, float* __restrict__ of32) {
  __shared__ u16 AT[2][128 * 64];
  __shared__ u16 BT[2][128 * 64];
  const int t = threadIdx.x;
  const int l = t & 63;
  const int w = t >> 6;
  const int wm = w >> 2;      // 0..1  (row group of 64)
  const int wn = w & 3;       // 0..3  (col group of 32)
  const int r16 = l & 15;
  const int half = l >> 4;

  const int gx = gridDim.x;
  const int nwg = gx * gridDim.y;
  int lin = blockIdx.y * gx + blockIdx.x;
  if ((nwg & 7) == 0) lin = (lin & 7) * (nwg >> 3) + (lin >> 3);
  const int bx = lin % gx;
  const int by = lin / gx;
  const size_t brow = (size_t)by * 128;
  const size_t bcol = (size_t)bx * 128;

  const int srow = w * 8 + (l >> 3);
  const int kel = ((l & 7) ^ (l >> 3)) * 8;
  const int nt = K >> 6;

  f32x4 acc[4][2] = {};

#define STAGE(tile, buf)                                                              \
  {                                                                                   \
    const int k0_ = (tile) << 6;                                                      \
    _Pragma("unroll")                                                                 \
    for (int q = 0; q < 2; ++q)                                                       \
      stage16(A + (brow + q * 64 + srow) * (size_t)lda + (k0_ + kel),                 \
              &AT[buf][q * 4096 + w * 512]);                                          \
    _Pragma("unroll")                                                                 \
    for (int q = 0; q < 2; ++q)                                                       \
      stage16(B + (bcol + q * 64 + srow) * (size_t)ldb + (k0_ + kel),                 \
              &BT[buf][q * 4096 + w * 512]);                                          \
  }

  STAGE(0, 0);

  for (int tt = 0; tt < nt; ++tt) {
    const int cur = tt & 1;
    __builtin_amdgcn_s_barrier();
    __builtin_amdgcn_sched_barrier(0);   // race safety: nothing hoists above barrier
    if (tt + 1 < nt) {
      STAGE(tt + 1, cur ^ 1);
      __builtin_amdgcn_sched_barrier(0); // pin staging issue before the wait
      asm volatile("s_waitcnt vmcnt(4)" ::: "memory");  // t's 4 done; t+1's in flight
    } else {
      asm volatile("s_waitcnt vmcnt(0)" ::: "memory");
    }

    bf16x8 af[4][2], bfr[2][2];
#pragma unroll
    for (int m = 0; m < 4; ++m) {
      const int row = wm * 64 + m * 16 + r16;
#pragma unroll
      for (int kk = 0; kk < 2; ++kk) {
        const int slot = (half + 4 * kk) ^ (r16 & 7);
        af[m][kk] = *reinterpret_cast<const bf16x8*>(&AT[cur][row * 64 + slot * 8]);
      }
    }
#pragma unroll
    for (int n = 0; n < 2; ++n) {
      const int row = wn * 32 + n * 16 + r16;
#pragma unroll
      for (int kk = 0; kk < 2; ++kk) {
        const int slot = (half + 4 * kk) ^ (r16 & 7);
        bfr[n][kk] = *reinterpret_cast<const bf16x8*>(&BT[cur][row * 64 + slot * 8]);
      }
    }
    __builtin_amdgcn_s_setprio(1);
#pragma unroll
    for (int m = 0; m < 4; ++m)
#pragma unroll
      for (int n = 0; n < 2; ++n)
#pragma unroll
        for (int kk = 0; kk < 2; ++kk)
          acc[m][n] = __builtin_amdgcn_mfma_f32_16x16x32_bf16(
              af[m][kk], bfr[n][kk], acc[m][n], 0, 0, 0);
    __builtin_amdgcn_s_setprio(0);
  }
#undef STAGE

  if constexpr (EPI == 0) {
    const float* bp = ((bcol >> 10) == 0) ? b0 : b1;
#pragma unroll
    for (int mg = 0; mg < 4; ++mg) {
#pragma unroll
      for (int n = 0; n < 2; ++n) {
        const int cc = wn * 32 + n * 16 + r16;
        const float bv = bp[((int)bcol & 1023) + cc];
#pragma unroll
        for (int q = 0; q < 4; ++q) {
          size_t row = brow + wm * 64 + mg * 16 + half * 4 + q;
          obf[row * (size_t)ldo + bcol + cc] = f2bf(acc[mg][n][q] + bv);
        }
      }
    }
  } else if constexpr (EPI == 4) {
#pragma unroll
    for (int n = 0; n < 2; ++n) {
      const int cc = wn * 32 + n * 16 + r16;
      const float invc = 1.0f / csp[bcol + cc];
#pragma unroll
      for (int mg = 0; mg < 4; ++mg) {
#pragma unroll
        for (int q = 0; q < 4; ++q) {
          size_t row = brow + wm * 64 + mg * 16 + half * 4 + q;
          obf[row * (size_t)ldo + bcol + cc] = f2bf((acc[mg][n][q] + b0[row]) * invc);
        }
      }
    }
  } else {
#pragma unroll
    for (int mg = 0; mg < 4; ++mg) {
#pragma unroll
      for (int n = 0; n < 2; ++n) {
#pragma unroll
        for (int q = 0; q < 4; ++q) {
          size_t row = brow + wm * 64 + mg * 16 + half * 4 + q;
          size_t col = bcol + wn * 32 + n * 16 + r16;
          of32[row * (size_t)ldo + col] = acc[mg][n][q];
        }
      }
    }
  }
}

// ---------------- GEMM C = A @ B^T  (m97 structure, fallback path) ----------------
template<int EPI, int AF32, int BF32>
__global__ __launch_bounds__(256)
void gemm_bt(const void* __restrict__ Av, const void* __restrict__ Bv, int K, int ldo,
             const float* __restrict__ bias, u16* __restrict__ obf,
             float* __restrict__ of32, const int* __restrict__ indp) {
  __shared__ u16 As[128 * 32];
  __shared__ u16 Bs[128 * 32];
  const int t = threadIdx.x;
  const int l = t & 63;
  const int w = t >> 6;
  const int wr = w >> 1;
  const int wc = w & 1;
  const int r16 = l & 15;
  const int half = l >> 4;

  const int gx = gridDim.x;
  const int nwg = gx * gridDim.y;
  int lin = blockIdx.y * gx + blockIdx.x;
  if ((nwg & 7) == 0) lin = (lin & 7) * (nwg >> 3) + (lin >> 3);
  const int bx = lin % gx;
  const int by = lin / gx;

  const size_t brow = (size_t)by * 128;
  const size_t bcol = (size_t)bx * 128;
  const int kel = (l & 3) * 8;
  const int lrow = l >> 2;

  f32x4 acc[4][4] = {};

  for (int k0 = 0; k0 < K; k0 += 32) {
#pragma unroll
    for (int c = 0; c < 2; ++c) {
      const int seg = c * 4 + w;
      const int r = seg * 16 + lrow;
      if constexpr (AF32) {
        const float* ga = (const float*)Av + (brow + r) * (size_t)K + (k0 + kel);
        float4 u0 = *reinterpret_cast<const float4*>(ga);
        float4 u1 = *reinterpret_cast<const float4*>(ga + 4);
        u16x8 o;
        o[0] = f2bf(u0.x); o[1] = f2bf(u0.y); o[2] = f2bf(u0.z); o[3] = f2bf(u0.w);
        o[4] = f2bf(u1.x); o[5] = f2bf(u1.y); o[6] = f2bf(u1.z); o[7] = f2bf(u1.w);
        *reinterpret_cast<u16x8*>(&As[seg * 512 + l * 8]) = o;
      } else {
        const u16* ga = (const u16*)Av + (brow + r) * (size_t)K + (k0 + kel);
        stage16(ga, &As[seg * 512]);
      }
      if constexpr (BF32) {
        const float* gb = (const float*)Bv + (bcol + r) * (size_t)K + (k0 + kel);
        float4 u0 = *reinterpret_cast<const float4*>(gb);
        float4 u1 = *reinterpret_cast<const float4*>(gb + 4);
        u16x8 o;
        o[0] = f2bf(u0.x); o[1] = f2bf(u0.y); o[2] = f2bf(u0.z); o[3] = f2bf(u0.w);
        o[4] = f2bf(u1.x); o[5] = f2bf(u1.y); o[6] = f2bf(u1.z); o[7] = f2bf(u1.w);
        *reinterpret_cast<u16x8*>(&Bs[seg * 512 + l * 8]) = o;
      } else {
        const u16* gb = (const u16*)Bv + (bcol + r) * (size_t)K + (k0 + kel);
        stage16(gb, &Bs[seg * 512]);
      }
    }
    __syncthreads();
    bf16x8 af[4], bfv[4];
#pragma unroll
    for (int m = 0; m < 4; ++m)
      af[m] = *reinterpret_cast<const bf16x8*>(&As[(wr * 64 + m * 16 + r16) * 32 + half * 8]);
#pragma unroll
    for (int n = 0; n < 4; ++n)
      bfv[n] = *reinterpret_cast<const bf16x8*>(&Bs[(wc * 64 + n * 16 + r16) * 32 + half * 8]);
#pragma unroll
    for (int m = 0; m < 4; ++m)
#pragma unroll
      for (int n = 0; n < 4; ++n)
        acc[m][n] = __builtin_amdgcn_mfma_f32_16x16x32_bf16(af[m], bfv[n], acc[m][n], 0, 0, 0);
    __syncthreads();
  }

  const int crow0 = wr * 64 + half * 4;
  const int ccol0 = wc * 64 + r16;

  if constexpr (EPI == 0) {
#pragma unroll
    for (int m = 0; m < 4; ++m) {
#pragma unroll
      for (int n = 0; n < 4; ++n) {
        const int cc = ccol0 + n * 16;
        const float bv = bias[bcol + cc];
#pragma unroll
        for (int q = 0; q < 4; ++q) {
          size_t idx = (brow + crow0 + m * 16 + q) * (size_t)ldo + (bcol + cc);
          obf[idx] = f2bf(acc[m][n][q] + bv);
        }
      }
    }
  } else if constexpr (EPI == 1) {
    const bool flip = (*indp == 0);
    const float cexp = 0.045084220027780106f;
#pragma unroll
    for (int m = 0; m < 4; ++m) {
#pragma unroll
      for (int n = 0; n < 4; ++n) {
        const int cc = ccol0 + n * 16;
#pragma unroll
        for (int q = 0; q < 4; ++q) {
          float s = acc[m][n][q];
          float x = flip ? (1.0f - s) : s;
          size_t idx = (brow + crow0 + m * 16 + q) * (size_t)ldo + (bcol + cc);
          of32[idx] = exp2f(x * cexp);
        }
      }
    }
  } else {
#pragma unroll
    for (int m = 0; m < 4; ++m) {
#pragma unroll
      for (int n = 0; n < 4; ++n) {
        const int cc = ccol0 + n * 16;
#pragma unroll
        for (int q = 0; q < 4; ++q) {
          size_t idx = (brow + crow0 + m * 16 + q) * (size_t)ldo + (bcol + cc);
          of32[idx] = acc[m][n][q];
        }
      }
    }
  }
}

// ---------------- column sums (f32 source, fallback) ----------------
__global__ void colsum_kernel(const float* __restrict__ E, float* __restrict__ cs) {
  const int col = blockIdx.x * 256 + threadIdx.x;
  const int r0 = blockIdx.y * 256;
  float s = 0.f;
  for (int r = r0; r < r0 + 256; ++r)
    s += E[(size_t)r * NT + col];
  atomicAdd(&cs[col], s);
}

// ---------------- normalize ----------------
__global__ void norm_kernel(float* __restrict__ w, const float* __restrict__ cs, int n4) {
  int i = blockIdx.x * blockDim.x + threadIdx.x;
  int stride = gridDim.x * blockDim.x;
  for (; i < n4; i += stride) {
    float4 v = reinterpret_cast<float4*>(w)[i];
    int j4 = i & (NT / 4 - 1);
    float4 c = reinterpret_cast<const float4*>(cs)[j4];
    v.x /= c.x; v.y /= c.y; v.z /= c.z; v.w /= c.w;
    reinterpret_cast<float4*>(w)[i] = v;
  }
}

__global__ void norm_bf16_kernel(const u16* __restrict__ e, float* __restrict__ w,
                                 const float* __restrict__ cs, int n4) {
  int i = blockIdx.x * blockDim.x + threadIdx.x;
  int stride = gridDim.x * blockDim.x;
  for (; i < n4; i += stride) {
    ushort4 ev = reinterpret_cast<const ushort4*>(e)[i];
    int j4 = i & (NT / 4 - 1);
    float4 c = reinterpret_cast<const float4*>(cs)[j4];
    float4 v;
    v.x = bf2f(ev.x) / c.x;
    v.y = bf2f(ev.y) / c.y;
    v.z = bf2f(ev.z) / c.z;
    v.w = bf2f(ev.w) / c.w;
    reinterpret_cast<float4*>(w)[i] = v;
  }
}

// ---- Vt[d][j] = Vb[j][d] (fallback transpose) ----
__global__ void vt_kernel(const u16* __restrict__ Vb, const float* __restrict__ cs,
                          u16* __restrict__ Vt) {
  __shared__ u16 tile[64][65];
  const int jb = blockIdx.x * 64;
  const int db = blockIdx.y * 64;
  const int t = threadIdx.x;
  {
    const int d = t & 63;
    const int j0 = t >> 6;
    for (int jj = j0; jj < 64; jj += 4)
      tile[jj][d] = Vb[(size_t)(jb + jj) * DM + db + d];
  }
  __syncthreads();
  {
    const int j = t & 63;
    const int d0 = t >> 6;
    const float inv = cs ? (1.0f / cs[jb + j]) : 1.0f;
    for (int dd = d0; dd < 64; dd += 4) {
      u16 raw = tile[j][dd];
      Vt[(size_t)(db + dd) * NT + jb + j] = cs ? f2bf(bf2f(raw) * inv) : raw;
    }
  }
}

extern "C" void kernel_launch(void* const* d_in, const int* in_sizes, int n_in,
                              void* d_out, int out_size, void* d_ws, size_t ws_size,
                              hipStream_t stream) {
  const float* X  = (const float*)d_in[0];
  const int* indp = (const int*)d_in[1];
  const float* Wq = (const float*)d_in[2];
  const float* bq = (const float*)d_in[3];
  const float* Wk = (const float*)d_in[4];
  const float* bk = (const float*)d_in[5];
  const float* Wv = (const float*)d_in[6];
  const float* bv = (const float*)d_in[7];

  float* attn_out = (float*)d_out;                       // [NT, DM]
  float* attn_w   = (float*)d_out + (size_t)NT * DM;     // [NT, NT]

  const size_t EB_BYTES = (size_t)NT * NT * 2;           // 128 MB
  const size_t QKV_BYTES = (size_t)NT * DM * 2;          // 16.8 MB
  const size_t need_fast = EB_BYTES + 4 * QKV_BYTES + NT * 4;

  if (ws_size >= need_fast) {
    // ---------------- FAST PATH ----------------
    // Layout: Eb | QKb (NT x 2048) | Vt (DM x NT) | Xb | Wvb | cs
    char* ws = (char*)d_ws;
    u16* Eb  = (u16*)ws;
    u16* QKb = (u16*)(ws + EB_BYTES);                    // [NT][2048]
    u16* Vt  = QKb + (size_t)NT * 2048;                  // [DM][NT]
    u16* Xb  = Vt + (size_t)DM * NT;                     // [NT][DM]
    u16* Wvb = Xb + (size_t)NT * DM;                     // [DM][DM]
    float* cs = (float*)(Wvb + (size_t)DM * DM);
    // Wq/Wk packed bf16 live in the dead Eb region: [2048][1024]
    u16* Wqkb = Eb;
    u16* Wqb = Wqkb;
    u16* Wkb = Wqkb + (size_t)DM * DM;

    cvt_all_kernel<<<2048, 256, 0, stream>>>(X, Wq, Wk, Wv, Xb, Wqb, Wkb, Wvb);

    // QK projection (fused): QKb = X @ [Wq;Wk]^T + [bq;bk]  (ldo = 2048)
    mega_bt<0><<<dim3(2048 / 128, NT / 128), 512, 0, stream>>>(
        Xb, Wqkb, DM, DM, DM, 2048, bq, bk, nullptr, QKb, nullptr);

    // QK^T + exp -> bf16 E, fused column sums (Q = QKb cols 0..1023, K = cols 1024..2047)
    hipMemsetAsync(cs, 0, NT * sizeof(float), stream);
    qkt_exp_256<<<dim3(NT / 256, NT / 256), 512, 0, stream>>>(
        QKb, QKb + 1024, DM, 2048, Eb, cs, indp);

    // Vt = (Wv @ X^T + bv[row]) / cs[col]  -> bf16 [DM][NT]
    mega_bt<4><<<dim3(NT / 128, DM / 128), 512, 0, stream>>>(
        Wvb, Xb, DM, DM, DM, NT, bv, nullptr, cs, Vt, nullptr);

    // attn_out = Eb @ Vt^T (EPI2)
    mega_bt<2><<<dim3(DM / 128, NT / 128), 512, 0, stream>>>(
        Eb, Vt, NT, NT, NT, DM, nullptr, nullptr, nullptr, nullptr, attn_out);

    // attn_w = Eb / cs
    norm_bf16_kernel<<<4096, 256, 0, stream>>>(Eb, attn_w, cs, NT * NT / 4);
  } else {
    // ---------------- FALLBACK (round-3 proven path) ----------------
    char* ws = (char*)d_ws;
    u16* Qb = (u16*)ws;  ws += QKV_BYTES;
    u16* Kb = (u16*)ws;  ws += QKV_BYTES;
    u16* Vb = (u16*)ws;  ws += QKV_BYTES;
    u16* Vt = (u16*)ws;  ws += QKV_BYTES;
    float* cs = (float*)ws;

    dim3 gqkv(DM / 128, NT / 128);
    gemm_bt<0, 1, 1><<<gqkv, 256, 0, stream>>>(X, Wq, DM, DM, bq, Qb, nullptr, nullptr);
    gemm_bt<0, 1, 1><<<gqkv, 256, 0, stream>>>(X, Wk, DM, DM, bk, Kb, nullptr, nullptr);
    gemm_bt<0, 1, 1><<<gqkv, 256, 0, stream>>>(X, Wv, DM, DM, bv, Vb, nullptr, nullptr);

    gemm_bt<1, 0, 0><<<dim3(NT / 128, NT / 128), 256, 0, stream>>>(
        Qb, Kb, DM, NT, nullptr, nullptr, attn_w, indp);

    hipMemsetAsync(cs, 0, NT * sizeof(float), stream);
    colsum_kernel<<<dim3(32, 32), 256, 0, stream>>>(attn_w, cs);
    norm_kernel<<<4096, 256, 0, stream>>>(attn_w, cs, NT * NT / 4);
    vt_kernel<<<dim3(NT / 64, DM / 64), 256, 0, stream>>>(Vb, nullptr, Vt);

    gemm_bt<2, 1, 0><<<dim3(DM / 128, NT / 128), 256, 0, stream>>>(
        attn_w, Vt, NT, DM, nullptr, nullptr, attn_out, nullptr);
  }
}